// Round 2
// baseline (283.108 us; speedup 1.0000x reference)
//
#include <hip/hip_runtime.h>

#define D_FEAT 32
#define SCAN_ITEMS 16
#define SCAN_BLOCK 256
#define SCAN_TILE (SCAN_BLOCK * SCAN_ITEMS)  // 4096 elements per block

// ---------- Phase 1: histogram of src ----------
__global__ void hist_kernel(const int* __restrict__ edge_index, int* __restrict__ cnt, int E) {
    int e = blockIdx.x * blockDim.x + threadIdx.x;
    if (e < E) atomicAdd(&cnt[edge_index[e]], 1);
}

// ---------- Phase 2a: per-block exclusive scan (in-place safe) ----------
__global__ void scan_block_kernel(int* __restrict__ data, int* __restrict__ bsum, int n) {
    __shared__ int lds[SCAN_BLOCK];
    const int t = threadIdx.x;
    const int base = blockIdx.x * SCAN_TILE + t * SCAN_ITEMS;

    int v[SCAN_ITEMS];
    int s = 0;
    #pragma unroll
    for (int i = 0; i < SCAN_ITEMS; ++i) {
        v[i] = (base + i < n) ? data[base + i] : 0;
        s += v[i];
    }
    lds[t] = s;
    __syncthreads();
    // Hillis-Steele inclusive scan over 256 thread-sums
    for (int d = 1; d < SCAN_BLOCK; d <<= 1) {
        int tmp = (t >= d) ? lds[t - d] : 0;
        __syncthreads();
        lds[t] += tmp;
        __syncthreads();
    }
    int excl = lds[t] - s;  // exclusive prefix of this thread within block
    if (t == SCAN_BLOCK - 1) bsum[blockIdx.x] = lds[SCAN_BLOCK - 1];

    int run = excl;
    #pragma unroll
    for (int i = 0; i < SCAN_ITEMS; ++i) {
        if (base + i < n) data[base + i] = run;
        run += v[i];
    }
}

// ---------- Phase 2b: scan the block totals (tiny, serial) ----------
__global__ void scan_partials_kernel(int* __restrict__ bsum, int nb) {
    if (blockIdx.x == 0 && threadIdx.x == 0) {
        int run = 0;
        for (int i = 0; i < nb; ++i) {
            int v = bsum[i];
            bsum[i] = run;
            run += v;
        }
    }
}

// ---------- Phase 2c: add block offsets ----------
__global__ void add_offsets_kernel(int* __restrict__ data, const int* __restrict__ bsum, int n) {
    int i = blockIdx.x * blockDim.x + threadIdx.x;
    if (i < n) data[i] += bsum[i / SCAN_TILE];
}

// ---------- Phase 3: scatter edges into CSR slots ----------
// off[] holds exclusive offsets; atomicAdd turns it into running cursors.
// After this kernel, off[n] == end of segment n (== start of segment n+1).
__global__ void scatter_kernel(const int* __restrict__ edge_index,
                               const float* __restrict__ edge_attr,
                               int* __restrict__ off,
                               unsigned long long* __restrict__ sorted,
                               int E) {
    int e = blockIdx.x * blockDim.x + threadIdx.x;
    if (e >= E) return;
    int s = edge_index[e];
    int dst = edge_index[E + e];
    unsigned int a = __float_as_uint(edge_attr[e]);
    int pos = atomicAdd(&off[s], 1);
    sorted[pos] = ((unsigned long long)a << 32) | (unsigned int)dst;
}

// ---------- Phase 4: gather-accumulate, one 32-lane group per node ----------
__global__ void gather_kernel(const unsigned long long* __restrict__ sorted,
                              const int* __restrict__ off,
                              const float* __restrict__ x,
                              float* __restrict__ out,
                              int n_nodes) {
    int g = (blockIdx.x * blockDim.x + threadIdx.x) >> 5;  // node id
    int lane = threadIdx.x & 31;                            // feature id
    if (g >= n_nodes) return;

    int end = off[g];
    int start = (g == 0) ? 0 : off[g - 1];

    float acc = 0.0f;
    for (int k = start; k < end; ++k) {
        unsigned long long p = sorted[k];
        int dst = (int)(unsigned int)(p & 0xffffffffull);
        float a = __uint_as_float((unsigned int)(p >> 32));
        acc += a * x[((long long)dst << 5) + lane];
    }
    out[((long long)g << 5) + lane] = acc;
}

extern "C" void kernel_launch(void* const* d_in, const int* in_sizes, int n_in,
                              void* d_out, int out_size, void* d_ws, size_t ws_size,
                              hipStream_t stream) {
    const int* edge_index = (const int*)d_in[0];    // [2, E] int32
    const float* edge_attr = (const float*)d_in[1]; // [E] f32
    const float* x = (const float*)d_in[2];         // [N, 32] f32
    float* out = (float*)d_out;                     // [N, 32] f32

    const int E = in_sizes[1];
    const int n_nodes = in_sizes[2] / D_FEAT;

    // Workspace layout
    char* ws = (char*)d_ws;
    int* off = (int*)ws;                                          // N ints
    size_t off_bytes = (size_t)n_nodes * sizeof(int);
    size_t bsum_off = (off_bytes + 255) & ~(size_t)255;
    int* bsum = (int*)(ws + bsum_off);                            // nb1 ints
    size_t sorted_off = (bsum_off + 4096 + 255) & ~(size_t)255;
    unsigned long long* sorted = (unsigned long long*)(ws + sorted_off);  // E u64

    const int block = 256;
    const int nb1 = (n_nodes + SCAN_TILE - 1) / SCAN_TILE;

    // Phase 0: zero counters
    hipMemsetAsync(off, 0, off_bytes, stream);

    // Phase 1: histogram
    hist_kernel<<<(E + block - 1) / block, block, 0, stream>>>(edge_index, off, E);

    // Phase 2: exclusive scan (block scan -> partials scan -> add)
    scan_block_kernel<<<nb1, SCAN_BLOCK, 0, stream>>>(off, bsum, n_nodes);
    scan_partials_kernel<<<1, 64, 0, stream>>>(bsum, nb1);
    add_offsets_kernel<<<(n_nodes + block - 1) / block, block, 0, stream>>>(off, bsum, n_nodes);

    // Phase 3: scatter into CSR slots (off becomes segment-end array)
    scatter_kernel<<<(E + block - 1) / block, block, 0, stream>>>(edge_index, edge_attr, off, sorted, E);

    // Phase 4: gather-accumulate, no atomics, coalesced output
    long long total_threads = (long long)n_nodes * D_FEAT;
    gather_kernel<<<(int)((total_threads + block - 1) / block), block, 0, stream>>>(
        sorted, off, x, out, n_nodes);
}